// Round 9
// baseline (390.284 us; speedup 1.0000x reference)
//
#include <hip/hip_runtime.h>
#include <hip/hip_fp16.h>
#include <math.h>

// ---------------------------------------------------------------------------
// dual GAT (2 branches x 4 GATConv layers), N=20000 nodes, E=320000 edges.
// R8 changes vs R7:
//  - CSR build rewritten as a zero-global-atomic bucketed counting sort
//    (64-node buckets): LDS histograms + dense offset scan + deterministic
//    slot scatter + per-bucket finalize. Kills fill_csr2's 13x HBM write
//    amplification (cross-XCD line bouncing) and 1.36M global atomics.
//  - bucket regions XCD-affine via blockIdx&7 grouping (perf heuristic only)
// ---------------------------------------------------------------------------

#define WAVE 64
#define NBKP 320   // padded bucket count (N/64 = 313 actual)

typedef _Float16 f16;
typedef f16 f16x8 __attribute__((ext_vector_type(8)));
typedef f16 f16x4 __attribute__((ext_vector_type(4)));
typedef float f32x4 __attribute__((ext_vector_type(4)));

// ---- stage 1: per-(block,bucket) counts (LDS hist, no global atomics) ----
// 256 blocks x 2 branches; group g=bx&7 handles buckets with (k&7)==g;
// slice s=bx>>3 covers edges t = s*256+tid (+32*256 stride).
__global__ __launch_bounds__(256) void bucket_count(
        const int* __restrict__ ei0, const int* __restrict__ ei1,
        int* __restrict__ carr, int nbuk, int E, int tot) {
    __shared__ int h[NBKP];
    int br = blockIdx.y;
    const int* ei = br ? ei1 : ei0;
    int g = blockIdx.x & 7, s = blockIdx.x >> 3;
    for (int i = threadIdx.x; i < NBKP; i += 256) h[i] = 0;
    __syncthreads();
    for (int t = s * 256 + threadIdx.x; t < tot; t += 32 * 256) {
        int dst = (t < E) ? ei[E + t] : (t - E);
        int k = dst >> 6;
        if ((k & 7) != g) continue;
        atomicAdd(&h[k], 1);
    }
    __syncthreads();
    int* c = carr + ((size_t)br * gridDim.x + blockIdx.x) * NBKP;
    for (int i = threadIdx.x; i < NBKP; i += 256) c[i] = h[i];
}

// ---- stage 2: offsets (in-place prefix over blocks) + bucket bases -------
__global__ __launch_bounds__(256) void bucket_scan(
        int* __restrict__ carr, int* __restrict__ bbase, int nblk, int nbuk) {
    __shared__ int tot_s[NBKP];
    int br = blockIdx.y;
    for (int k = threadIdx.x; k < nbuk; k += 256) {
        int run = 0;
        for (int b = 0; b < nblk; ++b) {
            size_t idx = ((size_t)br * nblk + b) * NBKP + k;
            int v = carr[idx];
            carr[idx] = run;          // prefix within bucket across blocks
            run += v;
        }
        tot_s[k] = run;
    }
    __syncthreads();
    if (threadIdx.x == 0) {
        int* bb = bbase + br * (nbuk + 1);
        int run = 0;
        for (int k = 0; k < nbuk; ++k) { bb[k] = run; run += tot_s[k]; }
        bb[nbuk] = run;               // == tot
    }
}

// ---- stage 3: deterministic-slot pair scatter into bucket regions --------
__global__ __launch_bounds__(256) void bucket_scatter(
        const int* __restrict__ ei0, const int* __restrict__ ei1,
        const int* __restrict__ carr, const int* __restrict__ bbase,
        long long* __restrict__ pbuf, int nbuk, int E, int tot) {
    __shared__ int base_s[NBKP];
    __shared__ int h[NBKP];
    int br = blockIdx.y;
    const int* ei = br ? ei1 : ei0;
    const int* offb = carr + ((size_t)br * gridDim.x + blockIdx.x) * NBKP;
    const int* bb = bbase + br * (nbuk + 1);
    long long* pb = pbuf + (size_t)br * tot;
    int g = blockIdx.x & 7, s = blockIdx.x >> 3;
    for (int i = threadIdx.x; i < NBKP; i += 256) {
        h[i] = 0;
        base_s[i] = (i < nbuk) ? (bb[i] + offb[i]) : 0;
    }
    __syncthreads();
    for (int t = s * 256 + threadIdx.x; t < tot; t += 32 * 256) {
        int src, dst;
        if (t < E) { src = ei[t]; dst = ei[E + t]; }
        else       { src = dst = t - E; }
        int k = dst >> 6;
        if ((k & 7) != g) continue;
        int r = atomicAdd(&h[k], 1);        // LDS rank
        pb[base_s[k] + r] = ((long long)dst << 32) | (unsigned)src;
    }
}

// ---- stage 4: per-bucket exact CSR + rowptr ------------------------------
__global__ __launch_bounds__(256) void bucket_finalize(
        const long long* __restrict__ pbuf, const int* __restrict__ bbase,
        int* __restrict__ rowptrb, int* __restrict__ csrb,
        int n, int nbuk, int tot, int np) {
    __shared__ int h64[64], excl[64], cur[64];
    int br = blockIdx.y, k = blockIdx.x;
    const int* bb = bbase + br * (nbuk + 1);
    const long long* pb = pbuf + (size_t)br * tot;
    int base = bb[k], endb = bb[k + 1], cnt = endb - base;
    int* rp = rowptrb + (size_t)br * np;
    int* cs = csrb + (size_t)br * tot;
    int d0 = k << 6;
    int nn = min(64, n - d0);
    if (threadIdx.x < 64) h64[threadIdx.x] = 0;
    __syncthreads();
    for (int i = threadIdx.x; i < cnt; i += 256) {
        int dst = (int)(pb[base + i] >> 32);
        atomicAdd(&h64[dst & 63], 1);
    }
    __syncthreads();
    if (threadIdx.x == 0) {
        int run = 0;
        for (int j = 0; j < 64; ++j) { excl[j] = run; run += h64[j]; }
    }
    __syncthreads();
    if (threadIdx.x < 64) cur[threadIdx.x] = excl[threadIdx.x];
    if (threadIdx.x < nn) rp[d0 + threadIdx.x] = base + excl[threadIdx.x];
    if (k == nbuk - 1 && threadIdx.x == 64) rp[n] = endb;
    __syncthreads();
    for (int i = threadIdx.x; i < cnt; i += 256) {
        long long p = pb[base + i];
        int dst = (int)(p >> 32), src = (int)(p & 0xffffffffLL);
        int slot = atomicAdd(&cur[dst & 63], 1);
        cs[base + slot] = src;
    }
}

// ---- score-weight tile: wsd[b][sc][k] = dot(W[k, hd*C:...], a_{s|d}[hd]) ---
__global__ __launch_bounds__(256) void wsd_kernel(
        const float* __restrict__ W0, const float* __restrict__ W1,
        const float* __restrict__ as0, const float* __restrict__ as1,
        const float* __restrict__ ad0, const float* __restrict__ ad1,
        f16* __restrict__ wsd, int fout, int H, int C) {
    int b = blockIdx.y;
    const float* W = b ? W1 : W0;
    const float* a_s = b ? as1 : as0;
    const float* a_d = b ? ad1 : ad0;
    f16* out = wsd + (size_t)b * 16 * 128;
    int k = blockIdx.x * 16 + (threadIdx.x & 15);
    int sc = threadIdx.x >> 4;
    float sum = 0.f;
    if (sc < 2 * H) {
        int hd = (sc < H) ? sc : sc - H;
        const float* a = (sc < H) ? a_s : a_d;
        const float4* Wr = (const float4*)(W + (size_t)k * fout + hd * C);
        const float4* ar = (const float4*)(a + hd * C);
        for (int c = 0; c < (C >> 2); ++c) {
            float4 wv = Wr[c]; float4 av = ar[c];
            sum += wv.x * av.x + wv.y * av.y + wv.z * av.z + wv.w * av.w;
        }
    }
    out[sc * 128 + k] = (f16)sum;
}

// ---- MFMA GEMM: h = x@W (f32 acc, fp16 out) + score cols ----------------
template <typename XT>
__global__ __launch_bounds__(256) void gemm_mfma(
        const XT* __restrict__ x0, const XT* __restrict__ x1,
        const float* __restrict__ W0, const float* __restrict__ W1,
        const f16* __restrict__ wsd,
        f16* __restrict__ hb, float* __restrict__ ssb, float* __restrict__ sdb,
        int n, int fout, int H) {
    __shared__ f16 xl[64 * 136];
    __shared__ f16 wl[80 * 136];
    int b = blockIdx.z;
    const XT* x = b ? x1 : x0;
    const float* W = b ? W1 : W0;
    f16* h = hb + (size_t)b * n * 128;
    float* ss = ssb + (size_t)b * n * 4;
    float* sd = sdb + (size_t)b * n * 4;
    int colbase = blockIdx.y * 64;
    bool last = (blockIdx.y == gridDim.y - 1);
    int lane = threadIdx.x & 63, w = threadIdx.x >> 6;

    {
        int c = threadIdx.x & 63, kb = (threadIdx.x >> 6) * 32;
        #pragma unroll 8
        for (int j = 0; j < 32; ++j)
            wl[c * 136 + kb + j] = (f16)W[(size_t)(kb + j) * fout + colbase + c];
    }
    if (last) {
        int c = threadIdx.x & 15, kb = (threadIdx.x >> 4) * 8;
        *(f16x8*)&wl[(64 + c) * 136 + kb] =
            *(const f16x8*)&wsd[(size_t)b * 2048 + c * 128 + kb];
    }
    __syncthreads();

    f16x8 B[5][4];
    #pragma unroll
    for (int ct = 0; ct < 5; ++ct)
        #pragma unroll
        for (int kc = 0; kc < 4; ++kc)
            B[ct][kc] = *(const f16x8*)
                &wl[(ct * 16 + (lane & 15)) * 136 + kc * 32 + (lane >> 4) * 8];

    for (int base = blockIdx.x * 64; base < n; base += gridDim.x * 64) {
        __syncthreads();
        {
            int r = threadIdx.x >> 2, k0 = (threadIdx.x & 3) * 32;
            int row = base + r;
            if (row < n) {
                if constexpr (sizeof(XT) == 4) {
                    const float4* x4 = (const float4*)x;
                    #pragma unroll
                    for (int j = 0; j < 8; ++j) {
                        float4 v = x4[(size_t)row * 32 + (k0 >> 2) + j];
                        f16x4 hv = {(f16)v.x, (f16)v.y, (f16)v.z, (f16)v.w};
                        *(f16x4*)&xl[r * 136 + k0 + 4 * j] = hv;
                    }
                } else {
                    const f16x8* x8 = (const f16x8*)x;
                    #pragma unroll
                    for (int j = 0; j < 4; ++j)
                        *(f16x8*)&xl[r * 136 + k0 + 8 * j] =
                            x8[(size_t)row * 16 + (k0 >> 3) + j];
                }
            } else {
                f16x4 z = {(f16)0.f, (f16)0.f, (f16)0.f, (f16)0.f};
                #pragma unroll
                for (int j = 0; j < 8; ++j)
                    *(f16x4*)&xl[r * 136 + k0 + 4 * j] = z;
            }
        }
        __syncthreads();

        f16x8 A[4];
        #pragma unroll
        for (int kc = 0; kc < 4; ++kc)
            A[kc] = *(const f16x8*)
                &xl[(w * 16 + (lane & 15)) * 136 + kc * 32 + (lane >> 4) * 8];

        f32x4 acc[5];
        #pragma unroll
        for (int ct = 0; ct < 5; ++ct) acc[ct] = (f32x4){0.f, 0.f, 0.f, 0.f};
        #pragma unroll
        for (int ct = 0; ct < 5; ++ct)
            #pragma unroll
            for (int kc = 0; kc < 4; ++kc)
                acc[ct] = __builtin_amdgcn_mfma_f32_16x16x32_f16(
                    A[kc], B[ct][kc], acc[ct], 0, 0, 0);

        int r0 = base + w * 16 + (lane >> 4) * 4;
        int c0 = lane & 15;
        #pragma unroll
        for (int ct = 0; ct < 4; ++ct) {
            int col = colbase + ct * 16 + c0;
            #pragma unroll
            for (int j = 0; j < 4; ++j) {
                int row = r0 + j;
                if (row < n) h[(size_t)row * fout + col] = (f16)acc[ct][j];
            }
        }
        if (last) {
            #pragma unroll
            for (int j = 0; j < 4; ++j) {
                int row = r0 + j;
                if (row < n) {
                    float v = acc[4][j];
                    if (c0 < H)          ss[(size_t)row * H + c0] = v;
                    else if (c0 < 2 * H) sd[(size_t)row * H + c0 - H] = v;
                }
            }
        }
    }
}

// ---- fused alpha + gather, 128-wide layers (4 heads x 32) ---------------
__global__ __launch_bounds__(256) void gather128_f(
        const __half2* __restrict__ h2, const float* __restrict__ ss,
        const float* __restrict__ sd, const int* __restrict__ rowptr,
        const int* __restrict__ csr, const float* __restrict__ bias,
        f16* __restrict__ out, int n) {
    int wid = threadIdx.x >> 6, lane = threadIdx.x & 63;
    int v = blockIdx.x * 4 + wid;
    if (v >= n) return;
    int beg = rowptr[v], end = rowptr[v + 1];
    int hd = lane >> 4;
    int sub = lane & 15;
    int hd16 = hd * 16;
    float sd_h = sd[v * 4 + hd];

    float acc0 = 0.f, acc1 = 0.f, den = 0.f;
    int i0 = beg;
    for (; i0 + 16 <= end; i0 += 16) {
        int myidx = csr[i0 + sub];
        float sc = ss[myidx * 4 + hd] + sd_h;
        sc = fmaxf(sc, 0.2f * sc);
        float w_reg = __expf(sc);
        #pragma unroll
        for (int j = 0; j < 16; ++j) {
            int s = __shfl(myidx, j);
            float w = __shfl(w_reg, hd16 + j);
            float2 f = __half22float2(h2[s * 64 + lane]);
            acc0 = fmaf(w, f.x, acc0);
            acc1 = fmaf(w, f.y, acc1);
            den += w;
        }
    }
    int rem = end - i0;
    if (rem > 0) {
        int myidx = (sub < rem) ? csr[i0 + sub] : -1;
        float w_reg = 0.f;
        if (myidx >= 0) {
            float sc = ss[myidx * 4 + hd] + sd_h;
            sc = fmaxf(sc, 0.2f * sc);
            w_reg = __expf(sc);
        }
        #pragma unroll 4
        for (int j = 0; j < rem; ++j) {
            int s = __shfl(myidx, j);
            float w = __shfl(w_reg, hd16 + j);
            float2 f = __half22float2(h2[s * 64 + lane]);
            acc0 = fmaf(w, f.x, acc0);
            acc1 = fmaf(w, f.y, acc1);
            den += w;
        }
    }

    float inv = 1.f / den;
    float2 b2 = ((const float2*)bias)[lane];
    float o0 = fmaxf(fmaf(acc0, inv, b2.x), 0.f);
    float o1 = fmaxf(fmaf(acc1, inv, b2.y), 0.f);
    __half2 ov = __floats2half2_rn(o0, o1);
    __builtin_nontemporal_store(*(unsigned int*)&ov,
                                (unsigned int*)&out[v * 128 + 2 * lane]);
}

// ---- fused alpha + gather, layer 4 (1 head x 64) ------------------------
template <int MODE>
__global__ __launch_bounds__(256) void gather64_f(
        const __half* __restrict__ h, const float* __restrict__ ss,
        const float* __restrict__ sd, const int* __restrict__ rowptr,
        const int* __restrict__ csr, const float* __restrict__ bias,
        float* __restrict__ out, int n) {
    int wid = threadIdx.x >> 6, lane = threadIdx.x & 63;
    int v = blockIdx.x * 4 + wid;
    if (v >= n) return;
    int beg = rowptr[v], end = rowptr[v + 1];
    int sub = lane & 15;
    float sd_v = sd[v];

    float acc = 0.f, den = 0.f;
    int i0 = beg;
    for (; i0 + 16 <= end; i0 += 16) {
        int myidx = csr[i0 + sub];
        float sc = ss[myidx] + sd_v;
        sc = fmaxf(sc, 0.2f * sc);
        float w_reg = __expf(sc);
        #pragma unroll
        for (int j = 0; j < 16; ++j) {
            int s = __shfl(myidx, j);
            float w = __shfl(w_reg, j);
            float f = __half2float(h[s * 64 + lane]);
            acc = fmaf(w, f, acc);
            den += w;
        }
    }
    int rem = end - i0;
    if (rem > 0) {
        int myidx = (sub < rem) ? csr[i0 + sub] : -1;
        float w_reg = 0.f;
        if (myidx >= 0) {
            float sc = ss[myidx] + sd_v;
            sc = fmaxf(sc, 0.2f * sc);
            w_reg = __expf(sc);
        }
        #pragma unroll 4
        for (int j = 0; j < rem; ++j) {
            int s = __shfl(myidx, j);
            float w = __shfl(w_reg, j);
            float f = __half2float(h[s * 64 + lane]);
            acc = fmaf(w, f, acc);
            den += w;
        }
    }

    float o = acc / den + bias[lane];
    float sg = 0.5f / (1.f + __expf(-o));
    if (MODE == 1) out[(size_t)v * 64 + lane] = sg;
    else           out[(size_t)v * 64 + lane] += sg;
}

extern "C" void kernel_launch(void* const* d_in, const int* in_sizes, int n_in,
                              void* d_out, int out_size, void* d_ws, size_t ws_size,
                              hipStream_t stream) {
    const int N = in_sizes[0] / 128;      // 20000
    const int E = in_sizes[1] / 2;        // 320000
    const int TOT = E + N;                // edges incl. self loops
    const int NP = N + 4;                 // rowptr stride
    const int NBUK = (N + 63) >> 6;       // 313 buckets of 64 nodes
    const int NBLK = 256;                 // count/scatter blocks per branch

    const float* x1 = (const float*)d_in[0];
    const int*   ei1 = (const int*)d_in[1];
    const float* x2 = (const float*)d_in[2];
    const int*   ei2 = (const int*)d_in[3];
    void* const* P0 = d_in + 4;
    void* const* P1 = d_in + 20;

    // workspace layout (8B-aligned chunks)
    char* w = (char*)d_ws;
    f16* bufX = (f16*)w;               w += (size_t)2 * N * 128 * 2;
    f16* bufH = (f16*)w;               w += (size_t)2 * N * 128 * 2;
    float* s_src = (float*)w;          w += (size_t)2 * N * 4 * 4;
    float* s_dst = (float*)w;          w += (size_t)2 * N * 4 * 4;
    int* rowptr = (int*)w;             w += (size_t)2 * NP * 4;
    int* csr_src = (int*)w;            w += (size_t)2 * TOT * 4;
    int* carr = (int*)w;               w += (size_t)2 * NBLK * NBKP * 4;
    int* bbase = (int*)w;              w += (size_t)2 * (NBUK + 1) * 4 + 8;
    long long* pbuf = (long long*)w;   w += (size_t)2 * TOT * 8;
    f16* wsd = (f16*)w;                w += (size_t)2 * 16 * 128 * 2;

    dim3 blk(256);
    int gWave  = (N + 3) / 4;             // wave-per-node kernels

    // ---- CSR build: bucketed counting sort, no global atomics -----------
    bucket_count<<<dim3(NBLK, 2), blk, 0, stream>>>(ei1, ei2, carr, NBUK, E, TOT);
    bucket_scan<<<dim3(1, 2), blk, 0, stream>>>(carr, bbase, NBLK, NBUK);
    bucket_scatter<<<dim3(NBLK, 2), blk, 0, stream>>>(ei1, ei2, carr, bbase,
                                                      pbuf, NBUK, E, TOT);
    bucket_finalize<<<dim3(NBUK, 2), blk, 0, stream>>>(pbuf, bbase, rowptr,
                                                       csr_src, N, NBUK, TOT, NP);

    // ---- layers 1..3 (128 -> 4x32, relu), gathers per-branch ------------
    for (int l = 0; l < 3; ++l) {
        wsd_kernel<<<dim3(8, 2), blk, 0, stream>>>(
            (const float*)P0[l*4+0], (const float*)P1[l*4+0],
            (const float*)P0[l*4+1], (const float*)P1[l*4+1],
            (const float*)P0[l*4+2], (const float*)P1[l*4+2],
            wsd, 128, 4, 32);
        if (l == 0)
            gemm_mfma<float><<<dim3(128, 2, 2), blk, 0, stream>>>(
                x1, x2,
                (const float*)P0[0], (const float*)P1[0],
                wsd, bufH, s_src, s_dst, N, 128, 4);
        else
            gemm_mfma<f16><<<dim3(128, 2, 2), blk, 0, stream>>>(
                bufX, bufX + (size_t)N * 128,
                (const float*)P0[l*4+0], (const float*)P1[l*4+0],
                wsd, bufH, s_src, s_dst, N, 128, 4);
        for (int b = 0; b < 2; ++b)
            gather128_f<<<gWave, blk, 0, stream>>>(
                (const __half2*)(bufH + (size_t)b * N * 128),
                s_src + (size_t)b * N * 4, s_dst + (size_t)b * N * 4,
                rowptr + (size_t)b * NP, csr_src + (size_t)b * TOT,
                (const float*)(b ? P1[l*4+3] : P0[l*4+3]),
                bufX + (size_t)b * N * 128, N);
    }

    // ---- layer 4 (128 -> 1x64, sigmoid fused into d_out) ----------------
    wsd_kernel<<<dim3(8, 2), blk, 0, stream>>>(
        (const float*)P0[12], (const float*)P1[12],
        (const float*)P0[13], (const float*)P1[13],
        (const float*)P0[14], (const float*)P1[14],
        wsd, 64, 1, 64);
    gemm_mfma<f16><<<dim3(128, 1, 2), blk, 0, stream>>>(
        bufX, bufX + (size_t)N * 128,
        (const float*)P0[12], (const float*)P1[12],
        wsd, bufH, s_src, s_dst, N, 64, 1);
    gather64_f<1><<<gWave, blk, 0, stream>>>(
        (const __half*)bufH, s_src, s_dst, rowptr, csr_src,
        (const float*)P0[15], (float*)d_out, N);
    gather64_f<2><<<gWave, blk, 0, stream>>>(
        (const __half*)(bufH + (size_t)N * 128), s_src + (size_t)N * 4,
        s_dst + (size_t)N * 4, rowptr + NP, csr_src + (size_t)TOT,
        (const float*)P1[15], (float*)d_out, N);
}

// Round 10
// 272.402 us; speedup vs baseline: 1.4328x; 1.4328x over previous
//
#include <hip/hip_runtime.h>
#include <hip/hip_fp16.h>
#include <math.h>

// ---------------------------------------------------------------------------
// dual GAT (2 branches x 4 GATConv layers), N=20000 nodes, E=320000 edges.
// R9 changes vs R8:
//  - bucket_scan (125us, 1-block serial-chain) split into bucket_scan1
//    (one block/bucket, parallel 256-wide load + LDS scan) and bucket_scan2
//    (512-thread LDS scan of bucket totals). Everything else unchanged.
// ---------------------------------------------------------------------------

#define WAVE 64
#define NBKP 320   // padded bucket count (N/64 = 313 actual)

typedef _Float16 f16;
typedef f16 f16x8 __attribute__((ext_vector_type(8)));
typedef f16 f16x4 __attribute__((ext_vector_type(4)));
typedef float f32x4 __attribute__((ext_vector_type(4)));

// ---- stage 1: per-(block,bucket) counts (LDS hist, no global atomics) ----
__global__ __launch_bounds__(256) void bucket_count(
        const int* __restrict__ ei0, const int* __restrict__ ei1,
        int* __restrict__ carr, int nbuk, int E, int tot) {
    __shared__ int h[NBKP];
    int br = blockIdx.y;
    const int* ei = br ? ei1 : ei0;
    int g = blockIdx.x & 7, s = blockIdx.x >> 3;
    for (int i = threadIdx.x; i < NBKP; i += 256) h[i] = 0;
    __syncthreads();
    for (int t = s * 256 + threadIdx.x; t < tot; t += 32 * 256) {
        int dst = (t < E) ? ei[E + t] : (t - E);
        int k = dst >> 6;
        if ((k & 7) != g) continue;
        atomicAdd(&h[k], 1);
    }
    __syncthreads();
    int* c = carr + ((size_t)br * gridDim.x + blockIdx.x) * NBKP;
    for (int i = threadIdx.x; i < NBKP; i += 256) c[i] = h[i];
}

// ---- stage 2a: per-bucket exclusive prefix over the 256 blocks -----------
// one block per bucket; parallel strided load + LDS Hillis-Steele scan.
__global__ __launch_bounds__(256) void bucket_scan1(
        int* __restrict__ carr, int* __restrict__ btot, int nblk) {
    __shared__ int smem[256];
    int br = blockIdx.y, k = blockIdx.x;
    size_t idx = ((size_t)br * nblk + threadIdx.x) * NBKP + k;
    int v = carr[idx];
    smem[threadIdx.x] = v;
    __syncthreads();
    #pragma unroll
    for (int off = 1; off < 256; off <<= 1) {
        int t = (threadIdx.x >= off) ? smem[threadIdx.x - off] : 0;
        __syncthreads();
        smem[threadIdx.x] += t;
        __syncthreads();
    }
    carr[idx] = smem[threadIdx.x] - v;            // exclusive prefix
    if (threadIdx.x == 255) btot[br * NBKP + k] = smem[255];
}

// ---- stage 2b: bucket bases (512-thread LDS scan over bucket totals) -----
__global__ __launch_bounds__(512) void bucket_scan2(
        const int* __restrict__ btot, int* __restrict__ bbase, int nbuk) {
    __shared__ int smem[512];
    int br = blockIdx.y;
    int v = (threadIdx.x < nbuk) ? btot[br * NBKP + threadIdx.x] : 0;
    smem[threadIdx.x] = v;
    __syncthreads();
    #pragma unroll
    for (int off = 1; off < 512; off <<= 1) {
        int t = (threadIdx.x >= off) ? smem[threadIdx.x - off] : 0;
        __syncthreads();
        smem[threadIdx.x] += t;
        __syncthreads();
    }
    int* bb = bbase + br * (nbuk + 1);
    if (threadIdx.x < nbuk) bb[threadIdx.x] = smem[threadIdx.x] - v;
    if (threadIdx.x == nbuk - 1) bb[nbuk] = smem[threadIdx.x];
}

// ---- stage 3: deterministic-slot pair scatter into bucket regions --------
__global__ __launch_bounds__(256) void bucket_scatter(
        const int* __restrict__ ei0, const int* __restrict__ ei1,
        const int* __restrict__ carr, const int* __restrict__ bbase,
        long long* __restrict__ pbuf, int nbuk, int E, int tot) {
    __shared__ int base_s[NBKP];
    __shared__ int h[NBKP];
    int br = blockIdx.y;
    const int* ei = br ? ei1 : ei0;
    const int* offb = carr + ((size_t)br * gridDim.x + blockIdx.x) * NBKP;
    const int* bb = bbase + br * (nbuk + 1);
    long long* pb = pbuf + (size_t)br * tot;
    int g = blockIdx.x & 7, s = blockIdx.x >> 3;
    for (int i = threadIdx.x; i < NBKP; i += 256) {
        h[i] = 0;
        base_s[i] = (i < nbuk) ? (bb[i] + offb[i]) : 0;
    }
    __syncthreads();
    for (int t = s * 256 + threadIdx.x; t < tot; t += 32 * 256) {
        int src, dst;
        if (t < E) { src = ei[t]; dst = ei[E + t]; }
        else       { src = dst = t - E; }
        int k = dst >> 6;
        if ((k & 7) != g) continue;
        int r = atomicAdd(&h[k], 1);        // LDS rank
        pb[base_s[k] + r] = ((long long)dst << 32) | (unsigned)src;
    }
}

// ---- stage 4: per-bucket exact CSR + rowptr ------------------------------
__global__ __launch_bounds__(256) void bucket_finalize(
        const long long* __restrict__ pbuf, const int* __restrict__ bbase,
        int* __restrict__ rowptrb, int* __restrict__ csrb,
        int n, int nbuk, int tot, int np) {
    __shared__ int h64[64], excl[64], cur[64];
    int br = blockIdx.y, k = blockIdx.x;
    const int* bb = bbase + br * (nbuk + 1);
    const long long* pb = pbuf + (size_t)br * tot;
    int base = bb[k], endb = bb[k + 1], cnt = endb - base;
    int* rp = rowptrb + (size_t)br * np;
    int* cs = csrb + (size_t)br * tot;
    int d0 = k << 6;
    int nn = min(64, n - d0);
    if (threadIdx.x < 64) h64[threadIdx.x] = 0;
    __syncthreads();
    for (int i = threadIdx.x; i < cnt; i += 256) {
        int dst = (int)(pb[base + i] >> 32);
        atomicAdd(&h64[dst & 63], 1);
    }
    __syncthreads();
    if (threadIdx.x == 0) {
        int run = 0;
        for (int j = 0; j < 64; ++j) { excl[j] = run; run += h64[j]; }
    }
    __syncthreads();
    if (threadIdx.x < 64) cur[threadIdx.x] = excl[threadIdx.x];
    if (threadIdx.x < nn) rp[d0 + threadIdx.x] = base + excl[threadIdx.x];
    if (k == nbuk - 1 && threadIdx.x == 64) rp[n] = endb;
    __syncthreads();
    for (int i = threadIdx.x; i < cnt; i += 256) {
        long long p = pb[base + i];
        int dst = (int)(p >> 32), src = (int)(p & 0xffffffffLL);
        int slot = atomicAdd(&cur[dst & 63], 1);
        cs[base + slot] = src;
    }
}

// ---- score-weight tile: wsd[b][sc][k] = dot(W[k, hd*C:...], a_{s|d}[hd]) ---
__global__ __launch_bounds__(256) void wsd_kernel(
        const float* __restrict__ W0, const float* __restrict__ W1,
        const float* __restrict__ as0, const float* __restrict__ as1,
        const float* __restrict__ ad0, const float* __restrict__ ad1,
        f16* __restrict__ wsd, int fout, int H, int C) {
    int b = blockIdx.y;
    const float* W = b ? W1 : W0;
    const float* a_s = b ? as1 : as0;
    const float* a_d = b ? ad1 : ad0;
    f16* out = wsd + (size_t)b * 16 * 128;
    int k = blockIdx.x * 16 + (threadIdx.x & 15);
    int sc = threadIdx.x >> 4;
    float sum = 0.f;
    if (sc < 2 * H) {
        int hd = (sc < H) ? sc : sc - H;
        const float* a = (sc < H) ? a_s : a_d;
        const float4* Wr = (const float4*)(W + (size_t)k * fout + hd * C);
        const float4* ar = (const float4*)(a + hd * C);
        for (int c = 0; c < (C >> 2); ++c) {
            float4 wv = Wr[c]; float4 av = ar[c];
            sum += wv.x * av.x + wv.y * av.y + wv.z * av.z + wv.w * av.w;
        }
    }
    out[sc * 128 + k] = (f16)sum;
}

// ---- MFMA GEMM: h = x@W (f32 acc, fp16 out) + score cols ----------------
template <typename XT>
__global__ __launch_bounds__(256) void gemm_mfma(
        const XT* __restrict__ x0, const XT* __restrict__ x1,
        const float* __restrict__ W0, const float* __restrict__ W1,
        const f16* __restrict__ wsd,
        f16* __restrict__ hb, float* __restrict__ ssb, float* __restrict__ sdb,
        int n, int fout, int H) {
    __shared__ f16 xl[64 * 136];
    __shared__ f16 wl[80 * 136];
    int b = blockIdx.z;
    const XT* x = b ? x1 : x0;
    const float* W = b ? W1 : W0;
    f16* h = hb + (size_t)b * n * 128;
    float* ss = ssb + (size_t)b * n * 4;
    float* sd = sdb + (size_t)b * n * 4;
    int colbase = blockIdx.y * 64;
    bool last = (blockIdx.y == gridDim.y - 1);
    int lane = threadIdx.x & 63, w = threadIdx.x >> 6;

    {
        int c = threadIdx.x & 63, kb = (threadIdx.x >> 6) * 32;
        #pragma unroll 8
        for (int j = 0; j < 32; ++j)
            wl[c * 136 + kb + j] = (f16)W[(size_t)(kb + j) * fout + colbase + c];
    }
    if (last) {
        int c = threadIdx.x & 15, kb = (threadIdx.x >> 4) * 8;
        *(f16x8*)&wl[(64 + c) * 136 + kb] =
            *(const f16x8*)&wsd[(size_t)b * 2048 + c * 128 + kb];
    }
    __syncthreads();

    f16x8 B[5][4];
    #pragma unroll
    for (int ct = 0; ct < 5; ++ct)
        #pragma unroll
        for (int kc = 0; kc < 4; ++kc)
            B[ct][kc] = *(const f16x8*)
                &wl[(ct * 16 + (lane & 15)) * 136 + kc * 32 + (lane >> 4) * 8];

    for (int base = blockIdx.x * 64; base < n; base += gridDim.x * 64) {
        __syncthreads();
        {
            int r = threadIdx.x >> 2, k0 = (threadIdx.x & 3) * 32;
            int row = base + r;
            if (row < n) {
                if constexpr (sizeof(XT) == 4) {
                    const float4* x4 = (const float4*)x;
                    #pragma unroll
                    for (int j = 0; j < 8; ++j) {
                        float4 v = x4[(size_t)row * 32 + (k0 >> 2) + j];
                        f16x4 hv = {(f16)v.x, (f16)v.y, (f16)v.z, (f16)v.w};
                        *(f16x4*)&xl[r * 136 + k0 + 4 * j] = hv;
                    }
                } else {
                    const f16x8* x8 = (const f16x8*)x;
                    #pragma unroll
                    for (int j = 0; j < 4; ++j)
                        *(f16x8*)&xl[r * 136 + k0 + 8 * j] =
                            x8[(size_t)row * 16 + (k0 >> 3) + j];
                }
            } else {
                f16x4 z = {(f16)0.f, (f16)0.f, (f16)0.f, (f16)0.f};
                #pragma unroll
                for (int j = 0; j < 8; ++j)
                    *(f16x4*)&xl[r * 136 + k0 + 4 * j] = z;
            }
        }
        __syncthreads();

        f16x8 A[4];
        #pragma unroll
        for (int kc = 0; kc < 4; ++kc)
            A[kc] = *(const f16x8*)
                &xl[(w * 16 + (lane & 15)) * 136 + kc * 32 + (lane >> 4) * 8];

        f32x4 acc[5];
        #pragma unroll
        for (int ct = 0; ct < 5; ++ct) acc[ct] = (f32x4){0.f, 0.f, 0.f, 0.f};
        #pragma unroll
        for (int ct = 0; ct < 5; ++ct)
            #pragma unroll
            for (int kc = 0; kc < 4; ++kc)
                acc[ct] = __builtin_amdgcn_mfma_f32_16x16x32_f16(
                    A[kc], B[ct][kc], acc[ct], 0, 0, 0);

        int r0 = base + w * 16 + (lane >> 4) * 4;
        int c0 = lane & 15;
        #pragma unroll
        for (int ct = 0; ct < 4; ++ct) {
            int col = colbase + ct * 16 + c0;
            #pragma unroll
            for (int j = 0; j < 4; ++j) {
                int row = r0 + j;
                if (row < n) h[(size_t)row * fout + col] = (f16)acc[ct][j];
            }
        }
        if (last) {
            #pragma unroll
            for (int j = 0; j < 4; ++j) {
                int row = r0 + j;
                if (row < n) {
                    float v = acc[4][j];
                    if (c0 < H)          ss[(size_t)row * H + c0] = v;
                    else if (c0 < 2 * H) sd[(size_t)row * H + c0 - H] = v;
                }
            }
        }
    }
}

// ---- fused alpha + gather, 128-wide layers (4 heads x 32) ---------------
__global__ __launch_bounds__(256) void gather128_f(
        const __half2* __restrict__ h2, const float* __restrict__ ss,
        const float* __restrict__ sd, const int* __restrict__ rowptr,
        const int* __restrict__ csr, const float* __restrict__ bias,
        f16* __restrict__ out, int n) {
    int wid = threadIdx.x >> 6, lane = threadIdx.x & 63;
    int v = blockIdx.x * 4 + wid;
    if (v >= n) return;
    int beg = rowptr[v], end = rowptr[v + 1];
    int hd = lane >> 4;
    int sub = lane & 15;
    int hd16 = hd * 16;
    float sd_h = sd[v * 4 + hd];

    float acc0 = 0.f, acc1 = 0.f, den = 0.f;
    int i0 = beg;
    for (; i0 + 16 <= end; i0 += 16) {
        int myidx = csr[i0 + sub];
        float sc = ss[myidx * 4 + hd] + sd_h;
        sc = fmaxf(sc, 0.2f * sc);
        float w_reg = __expf(sc);
        #pragma unroll
        for (int j = 0; j < 16; ++j) {
            int s = __shfl(myidx, j);
            float w = __shfl(w_reg, hd16 + j);
            float2 f = __half22float2(h2[s * 64 + lane]);
            acc0 = fmaf(w, f.x, acc0);
            acc1 = fmaf(w, f.y, acc1);
            den += w;
        }
    }
    int rem = end - i0;
    if (rem > 0) {
        int myidx = (sub < rem) ? csr[i0 + sub] : -1;
        float w_reg = 0.f;
        if (myidx >= 0) {
            float sc = ss[myidx * 4 + hd] + sd_h;
            sc = fmaxf(sc, 0.2f * sc);
            w_reg = __expf(sc);
        }
        #pragma unroll 4
        for (int j = 0; j < rem; ++j) {
            int s = __shfl(myidx, j);
            float w = __shfl(w_reg, hd16 + j);
            float2 f = __half22float2(h2[s * 64 + lane]);
            acc0 = fmaf(w, f.x, acc0);
            acc1 = fmaf(w, f.y, acc1);
            den += w;
        }
    }

    float inv = 1.f / den;
    float2 b2 = ((const float2*)bias)[lane];
    float o0 = fmaxf(fmaf(acc0, inv, b2.x), 0.f);
    float o1 = fmaxf(fmaf(acc1, inv, b2.y), 0.f);
    __half2 ov = __floats2half2_rn(o0, o1);
    __builtin_nontemporal_store(*(unsigned int*)&ov,
                                (unsigned int*)&out[v * 128 + 2 * lane]);
}

// ---- fused alpha + gather, layer 4 (1 head x 64) ------------------------
template <int MODE>
__global__ __launch_bounds__(256) void gather64_f(
        const __half* __restrict__ h, const float* __restrict__ ss,
        const float* __restrict__ sd, const int* __restrict__ rowptr,
        const int* __restrict__ csr, const float* __restrict__ bias,
        float* __restrict__ out, int n) {
    int wid = threadIdx.x >> 6, lane = threadIdx.x & 63;
    int v = blockIdx.x * 4 + wid;
    if (v >= n) return;
    int beg = rowptr[v], end = rowptr[v + 1];
    int sub = lane & 15;
    float sd_v = sd[v];

    float acc = 0.f, den = 0.f;
    int i0 = beg;
    for (; i0 + 16 <= end; i0 += 16) {
        int myidx = csr[i0 + sub];
        float sc = ss[myidx] + sd_v;
        sc = fmaxf(sc, 0.2f * sc);
        float w_reg = __expf(sc);
        #pragma unroll
        for (int j = 0; j < 16; ++j) {
            int s = __shfl(myidx, j);
            float w = __shfl(w_reg, j);
            float f = __half2float(h[s * 64 + lane]);
            acc = fmaf(w, f, acc);
            den += w;
        }
    }
    int rem = end - i0;
    if (rem > 0) {
        int myidx = (sub < rem) ? csr[i0 + sub] : -1;
        float w_reg = 0.f;
        if (myidx >= 0) {
            float sc = ss[myidx] + sd_v;
            sc = fmaxf(sc, 0.2f * sc);
            w_reg = __expf(sc);
        }
        #pragma unroll 4
        for (int j = 0; j < rem; ++j) {
            int s = __shfl(myidx, j);
            float w = __shfl(w_reg, j);
            float f = __half2float(h[s * 64 + lane]);
            acc = fmaf(w, f, acc);
            den += w;
        }
    }

    float o = acc / den + bias[lane];
    float sg = 0.5f / (1.f + __expf(-o));
    if (MODE == 1) out[(size_t)v * 64 + lane] = sg;
    else           out[(size_t)v * 64 + lane] += sg;
}

extern "C" void kernel_launch(void* const* d_in, const int* in_sizes, int n_in,
                              void* d_out, int out_size, void* d_ws, size_t ws_size,
                              hipStream_t stream) {
    const int N = in_sizes[0] / 128;      // 20000
    const int E = in_sizes[1] / 2;        // 320000
    const int TOT = E + N;                // edges incl. self loops
    const int NP = N + 4;                 // rowptr stride
    const int NBUK = (N + 63) >> 6;       // 313 buckets of 64 nodes
    const int NBLK = 256;                 // count/scatter blocks per branch

    const float* x1 = (const float*)d_in[0];
    const int*   ei1 = (const int*)d_in[1];
    const float* x2 = (const float*)d_in[2];
    const int*   ei2 = (const int*)d_in[3];
    void* const* P0 = d_in + 4;
    void* const* P1 = d_in + 20;

    // workspace layout (8B-aligned chunks)
    char* w = (char*)d_ws;
    f16* bufX = (f16*)w;               w += (size_t)2 * N * 128 * 2;
    f16* bufH = (f16*)w;               w += (size_t)2 * N * 128 * 2;
    float* s_src = (float*)w;          w += (size_t)2 * N * 4 * 4;
    float* s_dst = (float*)w;          w += (size_t)2 * N * 4 * 4;
    int* rowptr = (int*)w;             w += (size_t)2 * NP * 4;
    int* csr_src = (int*)w;            w += (size_t)2 * TOT * 4;
    int* carr = (int*)w;               w += (size_t)2 * NBLK * NBKP * 4;
    int* btot = (int*)w;               w += (size_t)2 * NBKP * 4;
    int* bbase = (int*)w;              w += (size_t)2 * (NBUK + 1) * 4 + 8;
    long long* pbuf = (long long*)w;   w += (size_t)2 * TOT * 8;
    f16* wsd = (f16*)w;                w += (size_t)2 * 16 * 128 * 2;

    dim3 blk(256);
    int gWave  = (N + 3) / 4;             // wave-per-node kernels

    // ---- CSR build: bucketed counting sort, no global atomics -----------
    bucket_count<<<dim3(NBLK, 2), blk, 0, stream>>>(ei1, ei2, carr, NBUK, E, TOT);
    bucket_scan1<<<dim3(NBUK, 2), blk, 0, stream>>>(carr, btot, NBLK);
    bucket_scan2<<<dim3(1, 2), dim3(512), 0, stream>>>(btot, bbase, NBUK);
    bucket_scatter<<<dim3(NBLK, 2), blk, 0, stream>>>(ei1, ei2, carr, bbase,
                                                      pbuf, NBUK, E, TOT);
    bucket_finalize<<<dim3(NBUK, 2), blk, 0, stream>>>(pbuf, bbase, rowptr,
                                                       csr_src, N, NBUK, TOT, NP);

    // ---- layers 1..3 (128 -> 4x32, relu), gathers per-branch ------------
    for (int l = 0; l < 3; ++l) {
        wsd_kernel<<<dim3(8, 2), blk, 0, stream>>>(
            (const float*)P0[l*4+0], (const float*)P1[l*4+0],
            (const float*)P0[l*4+1], (const float*)P1[l*4+1],
            (const float*)P0[l*4+2], (const float*)P1[l*4+2],
            wsd, 128, 4, 32);
        if (l == 0)
            gemm_mfma<float><<<dim3(128, 2, 2), blk, 0, stream>>>(
                x1, x2,
                (const float*)P0[0], (const float*)P1[0],
                wsd, bufH, s_src, s_dst, N, 128, 4);
        else
            gemm_mfma<f16><<<dim3(128, 2, 2), blk, 0, stream>>>(
                bufX, bufX + (size_t)N * 128,
                (const float*)P0[l*4+0], (const float*)P1[l*4+0],
                wsd, bufH, s_src, s_dst, N, 128, 4);
        for (int b = 0; b < 2; ++b)
            gather128_f<<<gWave, blk, 0, stream>>>(
                (const __half2*)(bufH + (size_t)b * N * 128),
                s_src + (size_t)b * N * 4, s_dst + (size_t)b * N * 4,
                rowptr + (size_t)b * NP, csr_src + (size_t)b * TOT,
                (const float*)(b ? P1[l*4+3] : P0[l*4+3]),
                bufX + (size_t)b * N * 128, N);
    }

    // ---- layer 4 (128 -> 1x64, sigmoid fused into d_out) ----------------
    wsd_kernel<<<dim3(8, 2), blk, 0, stream>>>(
        (const float*)P0[12], (const float*)P1[12],
        (const float*)P0[13], (const float*)P1[13],
        (const float*)P0[14], (const float*)P1[14],
        wsd, 64, 1, 64);
    gemm_mfma<f16><<<dim3(128, 1, 2), blk, 0, stream>>>(
        bufX, bufX + (size_t)N * 128,
        (const float*)P0[12], (const float*)P1[12],
        wsd, bufH, s_src, s_dst, N, 64, 1);
    gather64_f<1><<<gWave, blk, 0, stream>>>(
        (const __half*)bufH, s_src, s_dst, rowptr, csr_src,
        (const float*)P0[15], (float*)d_out, N);
    gather64_f<2><<<gWave, blk, 0, stream>>>(
        (const __half*)(bufH + (size_t)N * 128), s_src + (size_t)N * 4,
        s_dst + (size_t)N * 4, rowptr + NP, csr_src + (size_t)TOT,
        (const float*)P1[15], (float*)d_out, N);
}

// Round 11
// 238.173 us; speedup vs baseline: 1.6387x; 1.1437x over previous
//
#include <hip/hip_runtime.h>
#include <hip/hip_fp16.h>
#include <math.h>

// ---------------------------------------------------------------------------
// dual GAT (2 branches x 4 GATConv layers), N=20000 nodes, E=320000 edges.
// R10 changes vs R9:
//  - gathers restructured two-phase (issue 16 h-loads into regs, then FMA):
//    fixes VGPR=16 register starvation that serialized the gather burst
//  - bucket_count/scatter: &7 XCD filter removed (8x fewer edge reads/iters)
//  - one upfront wsd_all launch for all 4 layers (struct-of-pointers arg)
//  - gather64 branches merged into one kernel (single d_out write)
// ---------------------------------------------------------------------------

#define WAVE 64
#define NBKP 320   // padded bucket count (N/64 = 313 actual)

typedef _Float16 f16;
typedef f16 f16x8 __attribute__((ext_vector_type(8)));
typedef f16 f16x4 __attribute__((ext_vector_type(4)));
typedef float f32x4 __attribute__((ext_vector_type(4)));

// ---- stage 1: per-(block,bucket) counts (LDS hist, no global atomics) ----
__global__ __launch_bounds__(256) void bucket_count(
        const int* __restrict__ ei0, const int* __restrict__ ei1,
        int* __restrict__ carr, int nbuk, int E, int tot) {
    __shared__ int h[NBKP];
    int br = blockIdx.y;
    const int* ei = br ? ei1 : ei0;
    for (int i = threadIdx.x; i < NBKP; i += 256) h[i] = 0;
    __syncthreads();
    for (int t = blockIdx.x * 256 + threadIdx.x; t < tot; t += 256 * 256) {
        int dst = (t < E) ? ei[E + t] : (t - E);
        atomicAdd(&h[dst >> 6], 1);
    }
    __syncthreads();
    int* c = carr + ((size_t)br * gridDim.x + blockIdx.x) * NBKP;
    for (int i = threadIdx.x; i < NBKP; i += 256) c[i] = h[i];
}

// ---- stage 2a: per-bucket exclusive prefix over the 256 blocks -----------
__global__ __launch_bounds__(256) void bucket_scan1(
        int* __restrict__ carr, int* __restrict__ btot, int nblk) {
    __shared__ int smem[256];
    int br = blockIdx.y, k = blockIdx.x;
    size_t idx = ((size_t)br * nblk + threadIdx.x) * NBKP + k;
    int v = carr[idx];
    smem[threadIdx.x] = v;
    __syncthreads();
    #pragma unroll
    for (int off = 1; off < 256; off <<= 1) {
        int t = (threadIdx.x >= off) ? smem[threadIdx.x - off] : 0;
        __syncthreads();
        smem[threadIdx.x] += t;
        __syncthreads();
    }
    carr[idx] = smem[threadIdx.x] - v;            // exclusive prefix
    if (threadIdx.x == 255) btot[br * NBKP + k] = smem[255];
}

// ---- stage 2b: bucket bases (512-thread LDS scan over bucket totals) -----
__global__ __launch_bounds__(512) void bucket_scan2(
        const int* __restrict__ btot, int* __restrict__ bbase, int nbuk) {
    __shared__ int smem[512];
    int br = blockIdx.y;
    int v = (threadIdx.x < nbuk) ? btot[br * NBKP + threadIdx.x] : 0;
    smem[threadIdx.x] = v;
    __syncthreads();
    #pragma unroll
    for (int off = 1; off < 512; off <<= 1) {
        int t = (threadIdx.x >= off) ? smem[threadIdx.x - off] : 0;
        __syncthreads();
        smem[threadIdx.x] += t;
        __syncthreads();
    }
    int* bb = bbase + br * (nbuk + 1);
    if (threadIdx.x < nbuk) bb[threadIdx.x] = smem[threadIdx.x] - v;
    if (threadIdx.x == nbuk - 1) bb[nbuk] = smem[threadIdx.x];
}

// ---- stage 3: deterministic-slot pair scatter into bucket regions --------
__global__ __launch_bounds__(256) void bucket_scatter(
        const int* __restrict__ ei0, const int* __restrict__ ei1,
        const int* __restrict__ carr, const int* __restrict__ bbase,
        long long* __restrict__ pbuf, int nbuk, int E, int tot) {
    __shared__ int base_s[NBKP];
    __shared__ int h[NBKP];
    int br = blockIdx.y;
    const int* ei = br ? ei1 : ei0;
    const int* offb = carr + ((size_t)br * gridDim.x + blockIdx.x) * NBKP;
    const int* bb = bbase + br * (nbuk + 1);
    long long* pb = pbuf + (size_t)br * tot;
    for (int i = threadIdx.x; i < NBKP; i += 256) {
        h[i] = 0;
        base_s[i] = (i < nbuk) ? (bb[i] + offb[i]) : 0;
    }
    __syncthreads();
    for (int t = blockIdx.x * 256 + threadIdx.x; t < tot; t += 256 * 256) {
        int src, dst;
        if (t < E) { src = ei[t]; dst = ei[E + t]; }
        else       { src = dst = t - E; }
        int k = dst >> 6;
        int r = atomicAdd(&h[k], 1);        // LDS rank
        pb[base_s[k] + r] = ((long long)dst << 32) | (unsigned)src;
    }
}

// ---- stage 4: per-bucket exact CSR + rowptr ------------------------------
__global__ __launch_bounds__(256) void bucket_finalize(
        const long long* __restrict__ pbuf, const int* __restrict__ bbase,
        int* __restrict__ rowptrb, int* __restrict__ csrb,
        int n, int nbuk, int tot, int np) {
    __shared__ int h64[64], excl[64], cur[64];
    int br = blockIdx.y, k = blockIdx.x;
    const int* bb = bbase + br * (nbuk + 1);
    const long long* pb = pbuf + (size_t)br * tot;
    int base = bb[k], endb = bb[k + 1], cnt = endb - base;
    int* rp = rowptrb + (size_t)br * np;
    int* cs = csrb + (size_t)br * tot;
    int d0 = k << 6;
    int nn = min(64, n - d0);
    if (threadIdx.x < 64) h64[threadIdx.x] = 0;
    __syncthreads();
    for (int i = threadIdx.x; i < cnt; i += 256) {
        int dst = (int)(pb[base + i] >> 32);
        atomicAdd(&h64[dst & 63], 1);
    }
    __syncthreads();
    if (threadIdx.x == 0) {
        int run = 0;
        for (int j = 0; j < 64; ++j) { excl[j] = run; run += h64[j]; }
    }
    __syncthreads();
    if (threadIdx.x < 64) cur[threadIdx.x] = excl[threadIdx.x];
    if (threadIdx.x < nn) rp[d0 + threadIdx.x] = base + excl[threadIdx.x];
    if (k == nbuk - 1 && threadIdx.x == 64) rp[n] = endb;
    __syncthreads();
    for (int i = threadIdx.x; i < cnt; i += 256) {
        long long p = pb[base + i];
        int dst = (int)(p >> 32), src = (int)(p & 0xffffffffLL);
        int slot = atomicAdd(&cur[dst & 63], 1);
        cs[base + slot] = src;
    }
}

// ---- score-weight tiles for ALL layers in one launch ---------------------
struct WsdArgs {
    const float* W[8];    // [layer*2+branch]
    const float* as[8];
    const float* ad[8];
};

__global__ __launch_bounds__(256) void wsd_all(WsdArgs a, f16* __restrict__ wsd) {
    int l = blockIdx.z, b = blockIdx.y;
    int fout = (l == 3) ? 64 : 128;
    int H    = (l == 3) ? 1 : 4;
    int C    = (l == 3) ? 64 : 32;
    const float* W   = a.W[l * 2 + b];
    const float* a_s = a.as[l * 2 + b];
    const float* a_d = a.ad[l * 2 + b];
    f16* out = wsd + ((size_t)(l * 2 + b)) * 16 * 128;
    int k = blockIdx.x * 16 + (threadIdx.x & 15);
    int sc = threadIdx.x >> 4;
    float sum = 0.f;
    if (sc < 2 * H) {
        int hd = (sc < H) ? sc : sc - H;
        const float* av = (sc < H) ? a_s : a_d;
        const float4* Wr = (const float4*)(W + (size_t)k * fout + hd * C);
        const float4* ar = (const float4*)(av + hd * C);
        for (int c = 0; c < (C >> 2); ++c) {
            float4 wv = Wr[c]; float4 a4 = ar[c];
            sum += wv.x * a4.x + wv.y * a4.y + wv.z * a4.z + wv.w * a4.w;
        }
    }
    out[sc * 128 + k] = (f16)sum;
}

// ---- MFMA GEMM: h = x@W (f32 acc, fp16 out) + score cols ----------------
template <typename XT>
__global__ __launch_bounds__(256) void gemm_mfma(
        const XT* __restrict__ x0, const XT* __restrict__ x1,
        const float* __restrict__ W0, const float* __restrict__ W1,
        const f16* __restrict__ wsd,
        f16* __restrict__ hb, float* __restrict__ ssb, float* __restrict__ sdb,
        int n, int fout, int H) {
    __shared__ f16 xl[64 * 136];
    __shared__ f16 wl[80 * 136];
    int b = blockIdx.z;
    const XT* x = b ? x1 : x0;
    const float* W = b ? W1 : W0;
    f16* h = hb + (size_t)b * n * 128;
    float* ss = ssb + (size_t)b * n * 4;
    float* sd = sdb + (size_t)b * n * 4;
    int colbase = blockIdx.y * 64;
    bool last = (blockIdx.y == gridDim.y - 1);
    int lane = threadIdx.x & 63, w = threadIdx.x >> 6;

    {
        int c = threadIdx.x & 63, kb = (threadIdx.x >> 6) * 32;
        #pragma unroll 8
        for (int j = 0; j < 32; ++j)
            wl[c * 136 + kb + j] = (f16)W[(size_t)(kb + j) * fout + colbase + c];
    }
    if (last) {
        int c = threadIdx.x & 15, kb = (threadIdx.x >> 4) * 8;
        *(f16x8*)&wl[(64 + c) * 136 + kb] =
            *(const f16x8*)&wsd[(size_t)b * 2048 + c * 128 + kb];
    }
    __syncthreads();

    f16x8 B[5][4];
    #pragma unroll
    for (int ct = 0; ct < 5; ++ct)
        #pragma unroll
        for (int kc = 0; kc < 4; ++kc)
            B[ct][kc] = *(const f16x8*)
                &wl[(ct * 16 + (lane & 15)) * 136 + kc * 32 + (lane >> 4) * 8];

    for (int base = blockIdx.x * 64; base < n; base += gridDim.x * 64) {
        __syncthreads();
        {
            int r = threadIdx.x >> 2, k0 = (threadIdx.x & 3) * 32;
            int row = base + r;
            if (row < n) {
                if constexpr (sizeof(XT) == 4) {
                    const float4* x4 = (const float4*)x;
                    #pragma unroll
                    for (int j = 0; j < 8; ++j) {
                        float4 v = x4[(size_t)row * 32 + (k0 >> 2) + j];
                        f16x4 hv = {(f16)v.x, (f16)v.y, (f16)v.z, (f16)v.w};
                        *(f16x4*)&xl[r * 136 + k0 + 4 * j] = hv;
                    }
                } else {
                    const f16x8* x8 = (const f16x8*)x;
                    #pragma unroll
                    for (int j = 0; j < 4; ++j)
                        *(f16x8*)&xl[r * 136 + k0 + 8 * j] =
                            x8[(size_t)row * 16 + (k0 >> 3) + j];
                }
            } else {
                f16x4 z = {(f16)0.f, (f16)0.f, (f16)0.f, (f16)0.f};
                #pragma unroll
                for (int j = 0; j < 8; ++j)
                    *(f16x4*)&xl[r * 136 + k0 + 4 * j] = z;
            }
        }
        __syncthreads();

        f16x8 A[4];
        #pragma unroll
        for (int kc = 0; kc < 4; ++kc)
            A[kc] = *(const f16x8*)
                &xl[(w * 16 + (lane & 15)) * 136 + kc * 32 + (lane >> 4) * 8];

        f32x4 acc[5];
        #pragma unroll
        for (int ct = 0; ct < 5; ++ct) acc[ct] = (f32x4){0.f, 0.f, 0.f, 0.f};
        #pragma unroll
        for (int ct = 0; ct < 5; ++ct)
            #pragma unroll
            for (int kc = 0; kc < 4; ++kc)
                acc[ct] = __builtin_amdgcn_mfma_f32_16x16x32_f16(
                    A[kc], B[ct][kc], acc[ct], 0, 0, 0);

        int r0 = base + w * 16 + (lane >> 4) * 4;
        int c0 = lane & 15;
        #pragma unroll
        for (int ct = 0; ct < 4; ++ct) {
            int col = colbase + ct * 16 + c0;
            #pragma unroll
            for (int j = 0; j < 4; ++j) {
                int row = r0 + j;
                if (row < n) h[(size_t)row * fout + col] = (f16)acc[ct][j];
            }
        }
        if (last) {
            #pragma unroll
            for (int j = 0; j < 4; ++j) {
                int row = r0 + j;
                if (row < n) {
                    float v = acc[4][j];
                    if (c0 < H)          ss[(size_t)row * H + c0] = v;
                    else if (c0 < 2 * H) sd[(size_t)row * H + c0 - H] = v;
                }
            }
        }
    }
}

// ---- fused alpha + gather, 128-wide layers (4 heads x 32) ---------------
// two-phase chunks: issue all 16 h-loads into regs, then shfl-weight FMAs.
__global__ __launch_bounds__(256) void gather128_f(
        const __half2* __restrict__ h2, const float* __restrict__ ss,
        const float* __restrict__ sd, const int* __restrict__ rowptr,
        const int* __restrict__ csr, const float* __restrict__ bias,
        f16* __restrict__ out, int n) {
    int wid = threadIdx.x >> 6, lane = threadIdx.x & 63;
    int v = blockIdx.x * 4 + wid;
    if (v >= n) return;
    int beg = rowptr[v], end = rowptr[v + 1];
    int hd = lane >> 4;
    int sub = lane & 15;
    int hd16 = hd * 16;
    float sd_h = sd[v * 4 + hd];

    float acc0 = 0.f, acc1 = 0.f, den = 0.f;
    int i0 = beg;
    for (; i0 + 16 <= end; i0 += 16) {
        int myidx = csr[i0 + sub];
        float sc = ss[myidx * 4 + hd] + sd_h;
        sc = fmaxf(sc, 0.2f * sc);
        float w_reg = __expf(sc);
        unsigned hv[16];
        #pragma unroll
        for (int j = 0; j < 16; ++j) {
            int s = __shfl(myidx, j);
            hv[j] = *(const unsigned*)&h2[s * 64 + lane];
        }
        #pragma unroll
        for (int j = 0; j < 16; ++j) {
            float w = __shfl(w_reg, hd16 + j);
            float2 f = __half22float2(*(const __half2*)&hv[j]);
            acc0 = fmaf(w, f.x, acc0);
            acc1 = fmaf(w, f.y, acc1);
            den += w;
        }
    }
    int rem = end - i0;
    if (rem > 0) {
        int myidx = (sub < rem) ? csr[i0 + sub] : -1;
        float w_reg = 0.f;
        if (myidx >= 0) {
            float sc = ss[myidx * 4 + hd] + sd_h;
            sc = fmaxf(sc, 0.2f * sc);
            w_reg = __expf(sc);
        }
        #pragma unroll 4
        for (int j = 0; j < rem; ++j) {
            int s = __shfl(myidx, j);
            float w = __shfl(w_reg, hd16 + j);
            float2 f = __half22float2(h2[s * 64 + lane]);
            acc0 = fmaf(w, f.x, acc0);
            acc1 = fmaf(w, f.y, acc1);
            den += w;
        }
    }

    float inv = 1.f / den;
    float2 b2 = ((const float2*)bias)[lane];
    float o0 = fmaxf(fmaf(acc0, inv, b2.x), 0.f);
    float o1 = fmaxf(fmaf(acc1, inv, b2.y), 0.f);
    __half2 ov = __floats2half2_rn(o0, o1);
    __builtin_nontemporal_store(*(unsigned int*)&ov,
                                (unsigned int*)&out[v * 128 + 2 * lane]);
}

// ---- fused alpha + gather, layer 4, BOTH branches -> single d_out write --
__global__ __launch_bounds__(256) void gather64_both(
        const __half* __restrict__ h0, const __half* __restrict__ h1,
        const float* __restrict__ ss0, const float* __restrict__ ss1,
        const float* __restrict__ sd0, const float* __restrict__ sd1,
        const int* __restrict__ rp0, const int* __restrict__ rp1,
        const int* __restrict__ csr0, const int* __restrict__ csr1,
        const float* __restrict__ bias0, const float* __restrict__ bias1,
        float* __restrict__ out, int n) {
    int wid = threadIdx.x >> 6, lane = threadIdx.x & 63;
    int v = blockIdx.x * 4 + wid;
    if (v >= n) return;
    int sub = lane & 15;
    float og = 0.f;

    #pragma unroll
    for (int br = 0; br < 2; ++br) {
        const __half* h   = br ? h1 : h0;
        const float* ss   = br ? ss1 : ss0;
        const float* sd   = br ? sd1 : sd0;
        const int* rowptr = br ? rp1 : rp0;
        const int* csr    = br ? csr1 : csr0;
        const float* bias = br ? bias1 : bias0;
        int beg = rowptr[v], end = rowptr[v + 1];
        float sd_v = sd[v];
        float acc = 0.f, den = 0.f;
        int i0 = beg;
        for (; i0 + 16 <= end; i0 += 16) {
            int myidx = csr[i0 + sub];
            float sc = ss[myidx] + sd_v;
            sc = fmaxf(sc, 0.2f * sc);
            float w_reg = __expf(sc);
            unsigned short hv[16];
            #pragma unroll
            for (int j = 0; j < 16; ++j) {
                int s = __shfl(myidx, j);
                hv[j] = *(const unsigned short*)&h[s * 64 + lane];
            }
            #pragma unroll
            for (int j = 0; j < 16; ++j) {
                float w = __shfl(w_reg, j);
                float f = __half2float(*(const __half*)&hv[j]);
                acc = fmaf(w, f, acc);
                den += w;
            }
        }
        int rem = end - i0;
        if (rem > 0) {
            int myidx = (sub < rem) ? csr[i0 + sub] : -1;
            float w_reg = 0.f;
            if (myidx >= 0) {
                float sc = ss[myidx] + sd_v;
                sc = fmaxf(sc, 0.2f * sc);
                w_reg = __expf(sc);
            }
            #pragma unroll 4
            for (int j = 0; j < rem; ++j) {
                int s = __shfl(myidx, j);
                float w = __shfl(w_reg, j);
                float f = __half2float(h[s * 64 + lane]);
                acc = fmaf(w, f, acc);
                den += w;
            }
        }
        float o = acc / den + bias[lane];
        og += 0.5f / (1.f + __expf(-o));
    }
    out[(size_t)v * 64 + lane] = og;
}

extern "C" void kernel_launch(void* const* d_in, const int* in_sizes, int n_in,
                              void* d_out, int out_size, void* d_ws, size_t ws_size,
                              hipStream_t stream) {
    const int N = in_sizes[0] / 128;      // 20000
    const int E = in_sizes[1] / 2;        // 320000
    const int TOT = E + N;                // edges incl. self loops
    const int NP = N + 4;                 // rowptr stride
    const int NBUK = (N + 63) >> 6;       // 313 buckets of 64 nodes
    const int NBLK = 256;                 // count/scatter blocks per branch

    const float* x1 = (const float*)d_in[0];
    const int*   ei1 = (const int*)d_in[1];
    const float* x2 = (const float*)d_in[2];
    const int*   ei2 = (const int*)d_in[3];
    void* const* P0 = d_in + 4;
    void* const* P1 = d_in + 20;

    // workspace layout (8B-aligned chunks)
    char* w = (char*)d_ws;
    f16* bufX = (f16*)w;               w += (size_t)2 * N * 128 * 2;
    f16* bufH = (f16*)w;               w += (size_t)2 * N * 128 * 2;
    float* s_src = (float*)w;          w += (size_t)2 * N * 4 * 4;
    float* s_dst = (float*)w;          w += (size_t)2 * N * 4 * 4;
    int* rowptr = (int*)w;             w += (size_t)2 * NP * 4;
    int* csr_src = (int*)w;            w += (size_t)2 * TOT * 4;
    int* carr = (int*)w;               w += (size_t)2 * NBLK * NBKP * 4;
    int* btot = (int*)w;               w += (size_t)2 * NBKP * 4;
    int* bbase = (int*)w;              w += (size_t)2 * (NBUK + 1) * 4 + 8;
    long long* pbuf = (long long*)w;   w += (size_t)2 * TOT * 8;
    f16* wsd = (f16*)w;                w += (size_t)8 * 2048 * 2;

    dim3 blk(256);
    int gWave  = (N + 3) / 4;             // wave-per-node kernels

    // ---- all score-weight tiles (weights-only dependency) ---------------
    WsdArgs wa;
    for (int l = 0; l < 4; ++l) {
        int o = (l < 3) ? l * 4 : 12;
        wa.W[l * 2 + 0]  = (const float*)P0[o + 0];
        wa.W[l * 2 + 1]  = (const float*)P1[o + 0];
        wa.as[l * 2 + 0] = (const float*)P0[o + 1];
        wa.as[l * 2 + 1] = (const float*)P1[o + 1];
        wa.ad[l * 2 + 0] = (const float*)P0[o + 2];
        wa.ad[l * 2 + 1] = (const float*)P1[o + 2];
    }
    wsd_all<<<dim3(8, 2, 4), blk, 0, stream>>>(wa, wsd);

    // ---- CSR build: bucketed counting sort, no global atomics -----------
    bucket_count<<<dim3(NBLK, 2), blk, 0, stream>>>(ei1, ei2, carr, NBUK, E, TOT);
    bucket_scan1<<<dim3(NBUK, 2), blk, 0, stream>>>(carr, btot, NBLK);
    bucket_scan2<<<dim3(1, 2), dim3(512), 0, stream>>>(btot, bbase, NBUK);
    bucket_scatter<<<dim3(NBLK, 2), blk, 0, stream>>>(ei1, ei2, carr, bbase,
                                                      pbuf, NBUK, E, TOT);
    bucket_finalize<<<dim3(NBUK, 2), blk, 0, stream>>>(pbuf, bbase, rowptr,
                                                       csr_src, N, NBUK, TOT, NP);

    // ---- layers 1..3 (128 -> 4x32, relu), gathers per-branch ------------
    for (int l = 0; l < 3; ++l) {
        if (l == 0)
            gemm_mfma<float><<<dim3(128, 2, 2), blk, 0, stream>>>(
                x1, x2,
                (const float*)P0[0], (const float*)P1[0],
                wsd + (size_t)l * 4096, bufH, s_src, s_dst, N, 128, 4);
        else
            gemm_mfma<f16><<<dim3(128, 2, 2), blk, 0, stream>>>(
                bufX, bufX + (size_t)N * 128,
                (const float*)P0[l*4+0], (const float*)P1[l*4+0],
                wsd + (size_t)l * 4096, bufH, s_src, s_dst, N, 128, 4);
        for (int b = 0; b < 2; ++b)
            gather128_f<<<gWave, blk, 0, stream>>>(
                (const __half2*)(bufH + (size_t)b * N * 128),
                s_src + (size_t)b * N * 4, s_dst + (size_t)b * N * 4,
                rowptr + (size_t)b * NP, csr_src + (size_t)b * TOT,
                (const float*)(b ? P1[l*4+3] : P0[l*4+3]),
                bufX + (size_t)b * N * 128, N);
    }

    // ---- layer 4 (128 -> 1x64, sigmoid, both branches -> d_out) ---------
    gemm_mfma<f16><<<dim3(128, 1, 2), blk, 0, stream>>>(
        bufX, bufX + (size_t)N * 128,
        (const float*)P0[12], (const float*)P1[12],
        wsd + (size_t)3 * 4096, bufH, s_src, s_dst, N, 64, 1);
    gather64_both<<<gWave, blk, 0, stream>>>(
        (const __half*)bufH, (const __half*)(bufH + (size_t)N * 128),
        s_src, s_src + (size_t)N * 4, s_dst, s_dst + (size_t)N * 4,
        rowptr, rowptr + NP, csr_src, csr_src + (size_t)TOT,
        (const float*)P0[15], (const float*)P1[15],
        (float*)d_out, N);
}